// Round 2
// baseline (173.506 us; speedup 1.0000x reference)
//
#include <hip/hip_runtime.h>

// FeatureAttentionLayer: B=32, W=128, K=128, E=256, all fp32.
//   L[b,k,e] = sum_w x[b,w,k]*lin_w[e,w] + lin_b[e]
//   R[b,k,e] = sum_w x[b,w,k]*lin_w[e,128+w]
//   e[b,i,j] = sum_e a[e]*LReLU(L[b,i,e]+R[b,j,e]) + bias[i,j]
//            = sum_e (0.6a[e])*s + (0.4a[e])*|s|,  s = L+R   (exact identity)
//   att = softmax_j(e);  out[b,w,i] = sigmoid(sum_j att[b,i,j]*x[b,w,j])
//
// ws layout (floats): L @ 0 (1M), R @ 1M (1M), a6 @ 2M, a4 @ 2M+256.

#define WS_L  0
#define WS_R  1048576
#define WS_A6 2097152
#define WS_A4 2097408

// K1: L/R projection GEMM. grid (32 b, 2 kt, 8 et), 256 thr.
// thread: 4 k (kp), 2 e (ep); 16 accumulators; ping-pong register prefetch
// over w-chunks of 4 to cover L1/L2 latency.
__global__ __launch_bounds__(256) void k_linear(
    const float* __restrict__ x, const float* __restrict__ lin_w,
    const float* __restrict__ lin_b, const float* __restrict__ a,
    float* __restrict__ ws)
{
    const int t = threadIdx.x;
    const int b = blockIdx.x, kt = blockIdx.y, et = blockIdx.z;

    // fold a -> (0.6a, 0.4a) once (stream-ordered before K2 uses it)
    if (b == 0 && kt == 0 && et == 0) {
        float av = a[t];
        ws[WS_A6 + t] = 0.6f * av;
        ws[WS_A4 + t] = 0.4f * av;
    }

    const int ep = t & 15, kp = t >> 4;
    const int e0 = et * 32 + ep * 2;       // 2 consecutive e's
    const int k0 = kt * 64 + kp * 4;       // 4 consecutive k's

    float accL[2][4] = {{0.f}}, accR[2][4] = {{0.f}};   // [ee][kk]

    const float* xb  = x + b * 16384 + k0;          // x[b][w][k0..], w-stride 128
    const float* we0 = lin_w + (size_t)e0 * 256;
    const float* we1 = we0 + 256;

    float4 xA[4], lA[2], rA[2], xB[4], lB[2], rB[2];

#define K1_LOAD(X, L_, R_, wc) do { const int w4 = (wc) * 4;        \
    X[0] = *(const float4*)(xb + (w4 + 0) * 128);                   \
    X[1] = *(const float4*)(xb + (w4 + 1) * 128);                   \
    X[2] = *(const float4*)(xb + (w4 + 2) * 128);                   \
    X[3] = *(const float4*)(xb + (w4 + 3) * 128);                   \
    L_[0] = *(const float4*)(we0 + w4);                             \
    L_[1] = *(const float4*)(we1 + w4);                             \
    R_[0] = *(const float4*)(we0 + 128 + w4);                       \
    R_[1] = *(const float4*)(we1 + 128 + w4); } while (0)

#define K1_COMP(X, L_, R_) do {                                     \
    _Pragma("unroll") for (int ww = 0; ww < 4; ++ww) {              \
      _Pragma("unroll") for (int ee = 0; ee < 2; ++ee) {            \
        const float wl = ((const float*)&L_[ee])[ww];               \
        const float wr = ((const float*)&R_[ee])[ww];               \
        _Pragma("unroll") for (int kk = 0; kk < 4; ++kk) {          \
          const float xv = ((const float*)&X[ww])[kk];              \
          accL[ee][kk] = fmaf(xv, wl, accL[ee][kk]);                \
          accR[ee][kk] = fmaf(xv, wr, accR[ee][kk]); } } } } while (0)

    K1_LOAD(xA, lA, rA, 0);
    for (int wc = 0; wc < 32; wc += 2) {
        K1_LOAD(xB, lB, rB, wc + 1);
        K1_COMP(xA, lA, rA);
        K1_LOAD(xA, lA, rA, (wc + 2) & 31);   // wraps to 0 on last iter (harmless)
        K1_COMP(xB, lB, rB);
    }

    const float lb0 = lin_b[e0], lb1 = lin_b[e0 + 1];
    #pragma unroll
    for (int kk = 0; kk < 4; ++kk) {
        const int off = (b * 128 + k0 + kk) * 256 + e0;
        *(float2*)&ws[WS_L + off] = make_float2(accL[0][kk] + lb0, accL[1][kk] + lb1);
        *(float2*)&ws[WS_R + off] = make_float2(accR[0][kk], accR[1][kk]);
    }
}

// K2: fused logits + softmax + PV + sigmoid + transpose.
// grid (32 b, 16 i-tiles of 8 rows), 256 thr.
// phase1: ip = t>>5 (1 i-row per 32-lane half-wave), jp = t&31 (4 j's each);
//         3-op inner loop (add, fma, fma-with-|s|-modifier), ping-pong prefetch.
// phase2: iq = t&7 (1 i), wp = t>>3 (4 w's).
__global__ __launch_bounds__(256) void k_attn(
    const float* __restrict__ x, const float* __restrict__ bias,
    const float* __restrict__ ws, float* __restrict__ out)
{
    __shared__ float att[8 * 132];   // stride 132 spreads banks; 4.2 KB

    const int t = threadIdx.x;
    const int b = blockIdx.x, it = blockIdx.y;

    const int jp = t & 31, ip = t >> 5;
    const int i0 = it * 8 + ip;
    const float* Lg  = ws + WS_L + (size_t)(b * 128 + i0) * 256;
    const float* Rg  = ws + WS_R + (size_t)b * 32768 + jp * 256;  // j = jp+32*jj
    const float* a6g = ws + WS_A6;
    const float* a4g = ws + WS_A4;

    float acc1[4] = {0.f, 0.f, 0.f, 0.f};   // Σ 0.6a*s   per jj
    float acc2[4] = {0.f, 0.f, 0.f, 0.f};   // Σ 0.4a*|s|

    float4 lA, rA[4], s6A, s4A, lB, rB[4], s6B, s4B;

#define K2_LOAD(LV, RV, A6V, A4V, ec) do { const int e4 = (ec) * 4; \
    A6V = *(const float4*)(a6g + e4);                               \
    A4V = *(const float4*)(a4g + e4);                               \
    LV  = *(const float4*)(Lg + e4);                                \
    RV[0] = *(const float4*)(Rg + 0 * 8192 + e4);                   \
    RV[1] = *(const float4*)(Rg + 1 * 8192 + e4);                   \
    RV[2] = *(const float4*)(Rg + 2 * 8192 + e4);                   \
    RV[3] = *(const float4*)(Rg + 3 * 8192 + e4); } while (0)

#define K2_COMP(LV, RV, A6V, A4V) do {                              \
    _Pragma("unroll") for (int u = 0; u < 4; ++u) {                 \
      const float lu = ((const float*)&LV)[u];                      \
      const float a6 = ((const float*)&A6V)[u];                     \
      const float a4 = ((const float*)&A4V)[u];                     \
      _Pragma("unroll") for (int jj = 0; jj < 4; ++jj) {            \
        const float s = lu + ((const float*)&RV[jj])[u];            \
        acc1[jj] = fmaf(a6, s, acc1[jj]);                           \
        acc2[jj] = fmaf(a4, fabsf(s), acc2[jj]); } } } while (0)

    K2_LOAD(lA, rA, s6A, s4A, 0);
    for (int ec = 0; ec < 64; ec += 2) {
        K2_LOAD(lB, rB, s6B, s4B, ec + 1);
        K2_COMP(lA, rA, s6A, s4A);
        K2_LOAD(lA, rA, s6A, s4A, (ec + 2) & 63);  // wraps on last iter
        K2_COMP(lB, rB, s6B, s4B);
    }

    // bias + row softmax: row i0 lives in one 32-lane half-wave.
    float ev[4];
    #pragma unroll
    for (int jj = 0; jj < 4; ++jj)
        ev[jj] = acc1[jj] + acc2[jj] + bias[i0 * 128 + jp + 32 * jj];
    float m = fmaxf(fmaxf(ev[0], ev[1]), fmaxf(ev[2], ev[3]));
    #pragma unroll
    for (int d = 1; d <= 16; d <<= 1) m = fmaxf(m, __shfl_xor(m, d));
    float p[4], s = 0.f;
    #pragma unroll
    for (int jj = 0; jj < 4; ++jj) { p[jj] = __expf(ev[jj] - m); s += p[jj]; }
    #pragma unroll
    for (int d = 1; d <= 16; d <<= 1) s += __shfl_xor(s, d);
    const float inv = 1.f / s;
    #pragma unroll
    for (int jj = 0; jj < 4; ++jj)
        att[ip * 132 + jp + 32 * jj] = p[jj] * inv;

    __syncthreads();

    // phase 2: out[b,w,i] = sigmoid(sum_j att[i,j] * x[b,w,j])
    const int iq = t & 7, wp = t >> 3;
    float o[4] = {0.f, 0.f, 0.f, 0.f};   // [ww]
    const float* xb = x + b * 16384 + wp * 128;
    #pragma unroll 4
    for (int jc = 0; jc < 32; ++jc) {
        float4 av = *(const float4*)&att[iq * 132 + jc * 4];
        float4 xv[4];
        #pragma unroll
        for (int ww = 0; ww < 4; ++ww)
            xv[ww] = *(const float4*)(xb + ww * 4096 + jc * 4);
        #pragma unroll
        for (int u = 0; u < 4; ++u)
            #pragma unroll
            for (int ww = 0; ww < 4; ++ww)
                o[ww] = fmaf(((const float*)&av)[u],
                             ((const float*)&xv[ww])[u], o[ww]);
    }
    #pragma unroll
    for (int ww = 0; ww < 4; ++ww)
        out[(size_t)b * 16384 + (wp + 32 * ww) * 128 + it * 8 + iq]
            = 1.f / (1.f + __expf(-o[ww]));
}

extern "C" void kernel_launch(void* const* d_in, const int* in_sizes, int n_in,
                              void* d_out, int out_size, void* d_ws, size_t ws_size,
                              hipStream_t stream) {
    const float* x     = (const float*)d_in[0];
    const float* lin_w = (const float*)d_in[1];
    const float* lin_b = (const float*)d_in[2];
    const float* a     = (const float*)d_in[3];
    const float* bias  = (const float*)d_in[4];
    float* ws  = (float*)d_ws;
    float* out = (float*)d_out;

    k_linear<<<dim3(32, 2, 8), 256, 0, stream>>>(x, lin_w, lin_b, a, ws);
    k_attn  <<<dim3(32, 16), 256, 0, stream>>>(x, bias, ws, out);
}

// Round 3
// 70.027 us; speedup vs baseline: 2.4777x; 2.4777x over previous
//
#include <hip/hip_runtime.h>

// FeatureAttentionLayer: B=32, W=128, K=128, E=256, fp32.
//   L[i][e] = sum_w x[b][w][i]*lin_w[e][w] + lin_b[e]
//   R[j][e] = sum_w x[b][w][j]*lin_w[e][128+w]
//   e[i][j] = sum_e a[e]*LReLU(L+R) + bias = 0.6(dL[i]+dR[j]) + sum_e 0.4a|L+R| + bias
//   att = softmax_j; out[b][w][i] = sigmoid(sum_j att[i][j]*x[b][w][j])
//
// ws: P[b][r][k] (r<256: L^T row e with bias; r>=256: R^T row e), 2M floats;
//     a6 = 0.6a @ 2M, a4 = 0.4a @ 2M+256.
// Layout chosen so K2's hot loop reads P[b][256+e][j] with consecutive lanes
// on consecutive j (coalesced) — round-2 regression was 32 cache lines/instr
// on lane-strided R reads.

#define WS_A6  2097152
#define WS_A4  (2097152 + 256)

// K1: P[b][r][k] = sum_w x[b][w][k]*A[r][w], A[r]=lin_w[r][0:128] (r<256)
//     or lin_w[r-256][128:256]. grid (32 b, 8 rt), 256 thr.
// thread: kp=t&15 -> 8 k, ep=t>>4 -> 4 r rows. 128 FMA per 12-load chunk.
__global__ __launch_bounds__(256) void k_linear(
    const float* __restrict__ x, const float* __restrict__ lin_w,
    const float* __restrict__ lin_b, const float* __restrict__ a,
    float* __restrict__ ws)
{
    const int t = threadIdx.x;
    const int b = blockIdx.x, rt = blockIdx.y;

    if (b == 0 && rt == 0) {              // fold a once (K2 is stream-ordered after)
        float av = a[t];
        ws[WS_A6 + t] = 0.6f * av;
        ws[WS_A4 + t] = 0.4f * av;
    }

    const int kp = t & 15, ep = t >> 4;
    const int k0 = kp * 8;
    const int r0 = rt * 64 + ep * 4;
    const bool isL = (rt < 4);

    const float* xb = x + b * 16384 + k0;
    const float* Ar[4];
    #pragma unroll
    for (int ee = 0; ee < 4; ++ee) {
        const int r = r0 + ee;
        Ar[ee] = isL ? (lin_w + r * 256) : (lin_w + (r - 256) * 256 + 128);
    }

    float acc[4][8];
    #pragma unroll
    for (int ee = 0; ee < 4; ++ee)
        #pragma unroll
        for (int kk = 0; kk < 8; ++kk) acc[ee][kk] = 0.f;

    float4 x0A[4], x1A[4], wA[4], x0B[4], x1B[4], wB[4];

#define K1LD(X0, X1, WV, wc) do { const int w4 = (wc) * 4;                 \
    _Pragma("unroll") for (int ww = 0; ww < 4; ++ww) {                     \
      X0[ww] = *(const float4*)(xb + (w4 + ww) * 128);                     \
      X1[ww] = *(const float4*)(xb + (w4 + ww) * 128 + 4); }               \
    _Pragma("unroll") for (int ee = 0; ee < 4; ++ee)                       \
      WV[ee] = *(const float4*)(Ar[ee] + w4); } while (0)

#define K1CP(X0, X1, WV) do {                                              \
    _Pragma("unroll") for (int ww = 0; ww < 4; ++ww)                       \
      _Pragma("unroll") for (int ee = 0; ee < 4; ++ee) {                   \
        const float wv = ((const float*)&WV[ee])[ww];                      \
        _Pragma("unroll") for (int kk = 0; kk < 4; ++kk) {                 \
          acc[ee][kk]     = fmaf(((const float*)&X0[ww])[kk], wv, acc[ee][kk]);     \
          acc[ee][kk + 4] = fmaf(((const float*)&X1[ww])[kk], wv, acc[ee][kk + 4]); \
        } } } while (0)

    K1LD(x0A, x1A, wA, 0);
    for (int wc = 0; wc < 32; wc += 2) {
        K1LD(x0B, x1B, wB, wc + 1);
        K1CP(x0A, x1A, wA);
        K1LD(x0A, x1A, wA, (wc + 2) & 31);   // wraps to 0 on last iter (harmless)
        K1CP(x0B, x1B, wB);
    }

    #pragma unroll
    for (int ee = 0; ee < 4; ++ee) {
        const float lb = isL ? lin_b[r0 + ee] : 0.f;
        float* dst = ws + ((size_t)(b * 512 + r0 + ee) * 128 + k0);
        *(float4*)dst = make_float4(acc[ee][0] + lb, acc[ee][1] + lb,
                                    acc[ee][2] + lb, acc[ee][3] + lb);
        *(float4*)(dst + 4) = make_float4(acc[ee][4] + lb, acc[ee][5] + lb,
                                          acc[ee][6] + lb, acc[ee][7] + lb);
    }
}

// K2: fused logits + softmax + PV + sigmoid + transpose.
// grid (32 b, 8 it of 16 i-rows), 256 thr.
// phase1: lane tile 2i x 4j; R^T rows read coalesced; L^T tile in LDS.
// phase2: lane tile 2w x 4i.
__global__ __launch_bounds__(256) void k_attn(
    const float* __restrict__ x, const float* __restrict__ bias,
    const float* __restrict__ ws, float* __restrict__ out)
{
    __shared__ float Lt[256 * 16];    // Lt[e][il], il = i - it*16; 16 KB
    __shared__ float att[16 * 132];   // 8.4 KB

    const int t = threadIdx.x;
    const int b = blockIdx.x, it = blockIdx.y;
    const float* Pb = ws + (size_t)b * 65536;

    // stage L^T tile: Lt[e][0..15] = P[b][e][it*16 .. +15]  (coalesced 64B rows)
    {
        const float* src = Pb + it * 16;
        #pragma unroll
        for (int q = 0; q < 4; ++q) {
            const int idx = t + q * 256;           // 1024 float4 slots
            const int e = idx >> 2, fi = (idx & 3) * 4;
            *(float4*)&Lt[e * 16 + fi] = *(const float4*)(src + e * 128 + fi);
        }
    }
    __syncthreads();

    const int jp = t & 31, iq = t >> 5;
    const int j0 = jp * 4, il0 = iq * 2;
    const float* Rg  = Pb + 256 * 128 + j0;        // + e*128 per step
    const float* a6g = ws + WS_A6;
    const float* a4g = ws + WS_A4;

    float acc[2][4] = {{0.f}};                     // sum 0.4a*|s|
    float dl[2] = {0.f, 0.f};                      // sum 0.6a*L
    float dr[4] = {0.f, 0.f, 0.f, 0.f};            // sum 0.6a*R

    float4 rA[4], a6A, a4A; float2 lA[4];
    float4 rB[4], a6B, a4B; float2 lB[4];

#define K2LD(RV, LV, A6, A4, ec) do { const int e4 = (ec) * 4;             \
    A6 = *(const float4*)(a6g + e4);                                       \
    A4 = *(const float4*)(a4g + e4);                                       \
    _Pragma("unroll") for (int u = 0; u < 4; ++u) {                        \
      RV[u] = *(const float4*)(Rg + (e4 + u) * 128);                       \
      LV[u] = *(const float2*)&Lt[(e4 + u) * 16 + il0]; } } while (0)

#define K2CP(RV, LV, A6, A4) do {                                          \
    _Pragma("unroll") for (int u = 0; u < 4; ++u) {                        \
      const float a6u = ((const float*)&A6)[u];                            \
      const float a4u = ((const float*)&A4)[u];                            \
      const float l0 = LV[u].x, l1 = LV[u].y;                              \
      dl[0] = fmaf(a6u, l0, dl[0]);                                        \
      dl[1] = fmaf(a6u, l1, dl[1]);                                        \
      _Pragma("unroll") for (int jj = 0; jj < 4; ++jj) {                   \
        const float rv = ((const float*)&RV[u])[jj];                       \
        dr[jj] = fmaf(a6u, rv, dr[jj]);                                    \
        acc[0][jj] = fmaf(a4u, fabsf(l0 + rv), acc[0][jj]);                \
        acc[1][jj] = fmaf(a4u, fabsf(l1 + rv), acc[1][jj]); } } } while (0)

    K2LD(rA, lA, a6A, a4A, 0);
    for (int ec = 0; ec < 64; ec += 2) {
        K2LD(rB, lB, a6B, a4B, ec + 1);
        K2CP(rA, lA, a6A, a4A);
        K2LD(rA, lA, a6A, a4A, (ec + 2) & 63);
        K2CP(rB, lB, a6B, a4B);
    }

    // softmax over j (row i0+ii lives in one 32-lane half-wave)
    const int i0 = it * 16 + il0;
    #pragma unroll
    for (int ii = 0; ii < 2; ++ii) {
        const float4 bi = *(const float4*)(bias + (i0 + ii) * 128 + j0);
        float ev[4];
        #pragma unroll
        for (int jj = 0; jj < 4; ++jj)
            ev[jj] = acc[ii][jj] + dl[ii] + dr[jj] + ((const float*)&bi)[jj];
        float m = fmaxf(fmaxf(ev[0], ev[1]), fmaxf(ev[2], ev[3]));
        #pragma unroll
        for (int d = 1; d <= 16; d <<= 1) m = fmaxf(m, __shfl_xor(m, d));
        float p[4], s = 0.f;
        #pragma unroll
        for (int jj = 0; jj < 4; ++jj) { p[jj] = __expf(ev[jj] - m); s += p[jj]; }
        #pragma unroll
        for (int d = 1; d <= 16; d <<= 1) s += __shfl_xor(s, d);
        const float inv = 1.f / s;
        *(float4*)&att[(il0 + ii) * 132 + j0] =
            make_float4(p[0] * inv, p[1] * inv, p[2] * inv, p[3] * inv);
    }
    __syncthreads();

    // phase 2: out[b][w][i] = sigmoid(sum_j att[i][j]*x[b][w][j])
    const int iq2 = t & 3, wp = t >> 2;
    const int i4 = iq2 * 4, w0 = wp * 2;
    float o[2][4] = {{0.f}};
    const float* xb2 = x + b * 16384 + w0 * 128;
    #pragma unroll 4
    for (int jc = 0; jc < 32; ++jc) {
        float4 av[4], xv[2];
        #pragma unroll
        for (int q = 0; q < 4; ++q)
            av[q] = *(const float4*)&att[(i4 + q) * 132 + jc * 4];
        #pragma unroll
        for (int ww = 0; ww < 2; ++ww)
            xv[ww] = *(const float4*)(xb2 + ww * 128 + jc * 4);
        #pragma unroll
        for (int u = 0; u < 4; ++u)
            #pragma unroll
            for (int ww = 0; ww < 2; ++ww)
                #pragma unroll
                for (int q = 0; q < 4; ++q)
                    o[ww][q] = fmaf(((const float*)&xv[ww])[u],
                                    ((const float*)&av[q])[u], o[ww][q]);
    }
    #pragma unroll
    for (int ww = 0; ww < 2; ++ww) {
        float4 r;
        r.x = 1.f / (1.f + __expf(-o[ww][0]));
        r.y = 1.f / (1.f + __expf(-o[ww][1]));
        r.z = 1.f / (1.f + __expf(-o[ww][2]));
        r.w = 1.f / (1.f + __expf(-o[ww][3]));
        *(float4*)(out + (size_t)b * 16384 + (w0 + ww) * 128 + it * 16 + i4) = r;
    }
}

extern "C" void kernel_launch(void* const* d_in, const int* in_sizes, int n_in,
                              void* d_out, int out_size, void* d_ws, size_t ws_size,
                              hipStream_t stream) {
    const float* x     = (const float*)d_in[0];
    const float* lin_w = (const float*)d_in[1];
    const float* lin_b = (const float*)d_in[2];
    const float* a     = (const float*)d_in[3];
    const float* bias  = (const float*)d_in[4];
    float* ws  = (float*)d_ws;
    float* out = (float*)d_out;

    k_linear<<<dim3(32, 8), 256, 0, stream>>>(x, lin_w, lin_b, a, ws);
    k_attn  <<<dim3(32, 8), 256, 0, stream>>>(x, bias, ws, out);
}